// Round 10
// baseline (153.835 us; speedup 1.0000x reference)
//
#include <hip/hip_runtime.h>

#define N 8192
#define H 256
#define TOPK 16
#define NSEC 11
#define NEG_SLOPE 0.2
#define NB 256                 // K1 blocks (one per CU)
#define NT 256                 // threads per block
#define RPB (N / NB)           // 32 rows per block
#define NSL 8                  // slices per sector in slice_topk
#define SLICE (N / NSL)        // 1024 elements per slice
#define IDX_SENT 0x7fffffff

__device__ __forceinline__ bool better(double av, int ai, double bv, int bi) {
    return (av > bv) || (av == bv && ai < bi);
}

// ---------------------------------------------------------------------------
// K1: redundant v = W^T a per block (4 independent f64 chains), then s1/s2
// for this block's 32 rows (wave-per-row, float4 loads, f64 accumulate +
// shuffle reduce) — R8/R9-proven.
// ---------------------------------------------------------------------------
__global__ __launch_bounds__(NT) void compute_v_s(
    const float* __restrict__ E, const float* __restrict__ W,
    const float* __restrict__ a,
    float* __restrict__ s1f, double* __restrict__ s2g)
{
    __shared__ float sa[2 * H];
    __shared__ double sv1[H];
    __shared__ double sv2[H];

    int t = threadIdx.x;
    int blk = blockIdx.x;
    int lane = t & 63;
    int w = t >> 6;  // wave 0..3

    sa[t] = a[t];
    sa[t + H] = a[t + H];
    __syncthreads();

    {
        double a1_0 = 0.0, a1_1 = 0.0, a1_2 = 0.0, a1_3 = 0.0;
        double a2_0 = 0.0, a2_1 = 0.0, a2_2 = 0.0, a2_3 = 0.0;
        for (int j = 0; j < H; j += 4) {
            double w0 = (double)W[(j + 0) * H + t];
            double w1 = (double)W[(j + 1) * H + t];
            double w2 = (double)W[(j + 2) * H + t];
            double w3 = (double)W[(j + 3) * H + t];
            a1_0 += w0 * (double)sa[j + 0];
            a1_1 += w1 * (double)sa[j + 1];
            a1_2 += w2 * (double)sa[j + 2];
            a1_3 += w3 * (double)sa[j + 3];
            a2_0 += w0 * (double)sa[H + j + 0];
            a2_1 += w1 * (double)sa[H + j + 1];
            a2_2 += w2 * (double)sa[H + j + 2];
            a2_3 += w3 * (double)sa[H + j + 3];
        }
        sv1[t] = (a1_0 + a1_1) + (a1_2 + a1_3);
        sv2[t] = (a2_0 + a2_1) + (a2_2 + a2_3);
    }
    __syncthreads();

    for (int q = 0; q < RPB / 4; ++q) {
        int r_loc = w + 4 * q;                 // 0..31
        int row = blk * RPB + r_loc;
        const float4* Erow = (const float4*)(E + (size_t)row * H);
        float4 e = Erow[lane];
        int base = lane * 4;
        double acc1 = (double)e.x * sv1[base + 0] + (double)e.y * sv1[base + 1] +
                      (double)e.z * sv1[base + 2] + (double)e.w * sv1[base + 3];
        double acc2 = (double)e.x * sv2[base + 0] + (double)e.y * sv2[base + 1] +
                      (double)e.z * sv2[base + 2] + (double)e.w * sv2[base + 3];
        for (int o = 32; o > 0; o >>= 1) {
            acc1 += __shfl_down(acc1, o);
            acc2 += __shfl_down(acc2, o);
        }
        if (lane == 0) {
            s1f[row] = (float)acc1;
            s2g[row] = acc2;                   // f64 ordering key
        }
    }
}

// ---------------------------------------------------------------------------
// K2a: 88 blocks = 11 sectors x 8 slices of 1024. Thread t owns 4 consecutive
// elements -> ONE latency round (int4 act + int4 sec + 4 s2 doubles, all
// independent). LDS compact (cap = slice size, no fallback needed), wave-0
// 16-round register argmax -> sorted slice top-16 candidates.
// ---------------------------------------------------------------------------
__global__ __launch_bounds__(NT) void slice_topk(
    const double* __restrict__ s2g, const int* __restrict__ sec,
    const int* __restrict__ act,
    double* __restrict__ candV, int* __restrict__ candI,
    int* __restrict__ cnts)
{
    __shared__ double kv[SLICE];
    __shared__ int ki[SLICE];
    __shared__ int s_cnt;

    int bx = blockIdx.x;
    int c = bx >> 3;       // sector 0..10
    int sl = bx & 7;       // slice 0..7
    int t = threadIdx.x;
    int lane = t & 63;
    int w = t >> 6;

    if (t == 0) s_cnt = 0;
    __syncthreads();

    int j0 = sl * SLICE + 4 * t;
    int4 a4 = *(const int4*)(act + j0);
    int4 sv4 = *(const int4*)(sec + j0);
    double v0 = s2g[j0 + 0];
    double v1 = s2g[j0 + 1];
    double v2 = s2g[j0 + 2];
    double v3 = s2g[j0 + 3];

    unsigned pm = 0;
    if (a4.x != 0 && sv4.x == c) pm |= 1u;
    if (a4.y != 0 && sv4.y == c) pm |= 2u;
    if (a4.z != 0 && sv4.z == c) pm |= 4u;
    if (a4.w != 0 && sv4.w == c) pm |= 8u;
    int mycnt = __popc(pm);
    int pos = 0;
    if (mycnt > 0) pos = atomicAdd(&s_cnt, mycnt);
    if (pm & 1u) { kv[pos] = v0; ki[pos] = j0 + 0; ++pos; }
    if (pm & 2u) { kv[pos] = v1; ki[pos] = j0 + 1; ++pos; }
    if (pm & 4u) { kv[pos] = v2; ki[pos] = j0 + 2; ++pos; }
    if (pm & 8u) { kv[pos] = v3; ki[pos] = j0 + 3; ++pos; }
    __syncthreads();
    int total = s_cnt;     // <= SLICE by construction

    if (w == 0) {
        double cv[SLICE / 64];
        int ci[SLICE / 64];
        for (int p = 0; p < SLICE / 64; ++p) {
            int slot = p * 64 + lane;
            bool ok = (slot < total);
            cv[p] = ok ? kv[slot] : -INFINITY;
            ci[p] = ok ? ki[slot] : IDX_SENT;
        }
        for (int r = 0; r < TOPK; ++r) {
            double bv = cv[0];
            int bi = ci[0];
            for (int p = 1; p < SLICE / 64; ++p)
                if (better(cv[p], ci[p], bv, bi)) { bv = cv[p]; bi = ci[p]; }
            for (int o = 32; o > 0; o >>= 1) {
                double ov = __shfl_xor(bv, o);
                int oi = __shfl_xor(bi, o);
                if (better(ov, oi, bv, bi)) { bv = ov; bi = oi; }
            }
            if (bi != IDX_SENT) {
                for (int p = 0; p < SLICE / 64; ++p)
                    if (ci[p] == bi) { cv[p] = -INFINITY; ci[p] = IDX_SENT; }
            }
            if (lane == 0) {
                candV[bx * TOPK + r] = bv;
                candI[bx * TOPK + r] = bi;
            }
        }
        if (lane == 0) cnts[bx] = total;
    }
}

// ---------------------------------------------------------------------------
// K2b: one wave per sector. Merge 8 sorted 16-lists (= 128 candidates, 2 per
// lane) by 16 argmax rounds with remove-by-index (indices unique; sentinel
// removal is a no-op). Also m (sum of slice counts) and fill indices.
// ---------------------------------------------------------------------------
__global__ __launch_bounds__(64) void merge_topk(
    const double* __restrict__ candV, const int* __restrict__ candI,
    const int* __restrict__ cnts, const int* __restrict__ sec,
    const int* __restrict__ act,
    int* __restrict__ top_idx, int* __restrict__ fill_idx,
    int* __restrict__ m_arr)
{
    int c = blockIdx.x;
    int lane = threadIdx.x;

    const double* cbV = candV + (size_t)c * NSL * TOPK;   // 128 entries
    const int* cbI = candI + (size_t)c * NSL * TOPK;
    double v0 = cbV[lane];
    int i0 = cbI[lane];
    double v1 = cbV[lane + 64];
    int i1 = cbI[lane + 64];

    for (int r = 0; r < TOPK; ++r) {
        double bv;
        int bi;
        if (better(v0, i0, v1, i1)) { bv = v0; bi = i0; }
        else                        { bv = v1; bi = i1; }
        for (int o = 32; o > 0; o >>= 1) {
            double ov = __shfl_xor(bv, o);
            int oi = __shfl_xor(bi, o);
            if (better(ov, oi, bv, bi)) { bv = ov; bi = oi; }
        }
        if (i0 == bi)      { v0 = -INFINITY; i0 = IDX_SENT; }
        else if (i1 == bi) { v1 = -INFINITY; i1 = IDX_SENT; }
        if (lane == 0) top_idx[c * TOPK + r] = (bi == IDX_SENT) ? -1 : bi;
    }

    // m = min(16, total active in sector)
    int cl = (lane < NSL) ? cnts[c * NSL + lane] : 0;
    for (int o = 32; o > 0; o >>= 1) cl += __shfl_xor(cl, o);
    if (lane == 0) m_arr[c] = (cl < TOPK) ? cl : TOPK;

    // fill indices: first 16 j failing the predicate (usually 1 iteration)
    int cnt2 = 0;
    for (int basej = 0; basej < N && cnt2 < TOPK; basej += 64) {
        int j = basej + lane;
        bool fail = !((act[j] != 0) && (sec[j] == c));
        unsigned long long mask = __ballot(fail);
        if (fail) {
            int rank = cnt2 + __popcll(mask & ((1ull << lane) - 1));
            if (rank < TOPK) fill_idx[c * TOPK + rank] = j;
        }
        cnt2 += __popcll(mask);
    }
}

// ---------------------------------------------------------------------------
// K3: write outputs (weight, index-as-float, valid-as-float planes).
// ---------------------------------------------------------------------------
__global__ __launch_bounds__(NT) void write_out(const float* __restrict__ s1f,
                                                const double* __restrict__ s2g,
                                                const int* __restrict__ sec,
                                                const int* __restrict__ act,
                                                const int* __restrict__ top_idx,
                                                const int* __restrict__ fill_idx,
                                                const int* __restrict__ m_arr,
                                                float* __restrict__ out) {
    int gid = blockIdx.x * NT + threadIdx.x;  // N*TOPK total
    int i = gid >> 4;
    int slot = gid & 15;

    float wgt = 0.0f;
    float fidx;
    float fvalid = 0.0f;

    if (act[i] == 0) {
        fidx = (float)slot;  // all -inf row: stable top_k -> indices 0..15
    } else {
        int c = sec[i];
        int m = m_arr[c];
        if (slot < m) {
            int j = top_idx[c * TOPK + slot];
            double x = (double)s1f[i] + s2g[j];
            double attv = (x >= 0.0) ? x : NEG_SLOPE * x;
            wgt = (float)attv;
            fvalid = 1.0f;
            fidx = (float)j;
        } else {
            fidx = (float)fill_idx[c * TOPK + (slot - m)];
        }
    }

    out[gid] = wgt;
    out[N * TOPK + gid] = fidx;
    out[2 * N * TOPK + gid] = fvalid;
}

extern "C" void kernel_launch(void* const* d_in, const int* in_sizes, int n_in,
                              void* d_out, int out_size, void* d_ws, size_t ws_size,
                              hipStream_t stream) {
    const float* E = (const float*)d_in[0];
    const float* W = (const float*)d_in[1];
    const float* a = (const float*)d_in[2];
    const int* sec = (const int*)d_in[3];
    const int* act = (const int*)d_in[4];  // bool input uploaded as int32

    // workspace (~115 KB, 8-byte-aligned first) — within proven range
    char* ws = (char*)d_ws;
    double* s2g = (double*)ws;                     // N f64
    double* candV = s2g + N;                       // NSEC*NSL*TOPK = 1408 f64
    float* s1f = (float*)(candV + NSEC * NSL * TOPK);  // N f32
    int* candI = (int*)(s1f + N);                  // 1408 i32
    int* cnts = candI + NSEC * NSL * TOPK;         // NSEC*NSL = 88
    int* top_idx = cnts + NSEC * NSL;              // NSEC*TOPK
    int* fill_idx = top_idx + NSEC * TOPK;         // NSEC*TOPK
    int* m_arr = fill_idx + NSEC * TOPK;           // NSEC

    float* out = (float*)d_out;

    hipLaunchKernelGGL(compute_v_s, dim3(NB), dim3(NT), 0, stream,
                       E, W, a, s1f, s2g);
    hipLaunchKernelGGL(slice_topk, dim3(NSEC * NSL), dim3(NT), 0, stream,
                       s2g, sec, act, candV, candI, cnts);
    hipLaunchKernelGGL(merge_topk, dim3(NSEC), dim3(64), 0, stream,
                       candV, candI, cnts, sec, act, top_idx, fill_idx, m_arr);
    hipLaunchKernelGGL(write_out, dim3((N * TOPK) / NT), dim3(NT), 0, stream,
                       s1f, s2g, sec, act, top_idx, fill_idx, m_arr, out);
}

// Round 11
// 111.761 us; speedup vs baseline: 1.3765x; 1.3765x over previous
//
#include <hip/hip_runtime.h>

#define N 8192
#define H 256
#define TOPK 16
#define NSEC 11
#define NEG_SLOPE 0.2
#define NB 256                 // K1 blocks (one per CU)
#define NT 256                 // threads per block
#define RPB (N / NB)           // 32 rows per block
#define NSL 8                  // slices per sector in slice_topk
#define SLICE (N / NSL)        // 1024 elements per slice
#define IDX_SENT 0x7fffffff

__device__ __forceinline__ bool better(double av, int ai, double bv, int bi) {
    return (av > bv) || (av == bv && ai < bi);
}

// ---------------------------------------------------------------------------
// K1: redundant v = W^T a per block (4 independent f64 chains), then s1/s2
// for this block's 32 rows (wave-per-row, float4 loads, f64 accumulate +
// shuffle reduce) — R8/R9/R10-proven.
// ---------------------------------------------------------------------------
__global__ __launch_bounds__(NT) void compute_v_s(
    const float* __restrict__ E, const float* __restrict__ W,
    const float* __restrict__ a,
    float* __restrict__ s1f, double* __restrict__ s2g)
{
    __shared__ float sa[2 * H];
    __shared__ double sv1[H];
    __shared__ double sv2[H];

    int t = threadIdx.x;
    int blk = blockIdx.x;
    int lane = t & 63;
    int w = t >> 6;  // wave 0..3

    sa[t] = a[t];
    sa[t + H] = a[t + H];
    __syncthreads();

    {
        double a1_0 = 0.0, a1_1 = 0.0, a1_2 = 0.0, a1_3 = 0.0;
        double a2_0 = 0.0, a2_1 = 0.0, a2_2 = 0.0, a2_3 = 0.0;
        for (int j = 0; j < H; j += 4) {
            double w0 = (double)W[(j + 0) * H + t];
            double w1 = (double)W[(j + 1) * H + t];
            double w2 = (double)W[(j + 2) * H + t];
            double w3 = (double)W[(j + 3) * H + t];
            a1_0 += w0 * (double)sa[j + 0];
            a1_1 += w1 * (double)sa[j + 1];
            a1_2 += w2 * (double)sa[j + 2];
            a1_3 += w3 * (double)sa[j + 3];
            a2_0 += w0 * (double)sa[H + j + 0];
            a2_1 += w1 * (double)sa[H + j + 1];
            a2_2 += w2 * (double)sa[H + j + 2];
            a2_3 += w3 * (double)sa[H + j + 3];
        }
        sv1[t] = (a1_0 + a1_1) + (a1_2 + a1_3);
        sv2[t] = (a2_0 + a2_1) + (a2_2 + a2_3);
    }
    __syncthreads();

    for (int q = 0; q < RPB / 4; ++q) {
        int r_loc = w + 4 * q;                 // 0..31
        int row = blk * RPB + r_loc;
        const float4* Erow = (const float4*)(E + (size_t)row * H);
        float4 e = Erow[lane];
        int base = lane * 4;
        double acc1 = (double)e.x * sv1[base + 0] + (double)e.y * sv1[base + 1] +
                      (double)e.z * sv1[base + 2] + (double)e.w * sv1[base + 3];
        double acc2 = (double)e.x * sv2[base + 0] + (double)e.y * sv2[base + 1] +
                      (double)e.z * sv2[base + 2] + (double)e.w * sv2[base + 3];
        for (int o = 32; o > 0; o >>= 1) {
            acc1 += __shfl_down(acc1, o);
            acc2 += __shfl_down(acc2, o);
        }
        if (lane == 0) {
            s1f[row] = (float)acc1;
            s2g[row] = acc2;                   // f64 ordering key
        }
    }
}

// ---------------------------------------------------------------------------
// K2a: 88 blocks = 11 sectors x 8 slices of 1024. Hierarchical selection with
// max 4 candidates per lane (12 VGPRs — no scratch spill, unlike R8-R10's
// 16-element arrays at VGPR_Count=48):
//   wave w: 16-round shuffle argmax over its 256 elements -> sorted 16-list
//   wave 0: merge 4x16 = 64 candidates (1/lane) in 16 more rounds.
// No LDS compaction, no atomics, one global-load latency round.
// ---------------------------------------------------------------------------
__global__ __launch_bounds__(NT) void slice_topk(
    const double* __restrict__ s2g, const int* __restrict__ sec,
    const int* __restrict__ act,
    double* __restrict__ candV, int* __restrict__ candI,
    int* __restrict__ cnts)
{
    __shared__ double wV[4][TOPK];
    __shared__ int wI[4][TOPK];
    __shared__ int wCnt[4];

    int bx = blockIdx.x;
    int c = bx >> 3;       // sector 0..10
    int sl = bx & 7;       // slice 0..7
    int t = threadIdx.x;
    int lane = t & 63;
    int w = t >> 6;

    // one latency round: int4 act + int4 sec + 2x double2 s2
    int j0 = sl * SLICE + 4 * t;
    int4 a4 = *(const int4*)(act + j0);
    int4 s4 = *(const int4*)(sec + j0);
    double2 d01 = *(const double2*)(s2g + j0);
    double2 d23 = *(const double2*)(s2g + j0 + 2);

    bool p0 = (a4.x != 0) && (s4.x == c);
    bool p1 = (a4.y != 0) && (s4.y == c);
    bool p2 = (a4.z != 0) && (s4.z == c);
    bool p3 = (a4.w != 0) && (s4.w == c);

    double v[4];
    int ix[4];
    v[0] = p0 ? d01.x : -INFINITY;  ix[0] = p0 ? (j0 + 0) : IDX_SENT;
    v[1] = p1 ? d01.y : -INFINITY;  ix[1] = p1 ? (j0 + 1) : IDX_SENT;
    v[2] = p2 ? d23.x : -INFINITY;  ix[2] = p2 ? (j0 + 2) : IDX_SENT;
    v[3] = p3 ? d23.y : -INFINITY;  ix[3] = p3 ? (j0 + 3) : IDX_SENT;

    int cnt = __popcll(__ballot(p0)) + __popcll(__ballot(p1)) +
              __popcll(__ballot(p2)) + __popcll(__ballot(p3));

    // per-wave top-16 of this wave's 256 elements
    for (int r = 0; r < TOPK; ++r) {
        double bv = v[0];
        int bi = ix[0];
#pragma unroll
        for (int p = 1; p < 4; ++p)
            if (better(v[p], ix[p], bv, bi)) { bv = v[p]; bi = ix[p]; }
        for (int o = 32; o > 0; o >>= 1) {
            double ov = __shfl_xor(bv, o);
            int oi = __shfl_xor(bi, o);
            if (better(ov, oi, bv, bi)) { bv = ov; bi = oi; }
        }
#pragma unroll
        for (int p = 0; p < 4; ++p)
            if (ix[p] == bi) { v[p] = -INFINITY; ix[p] = IDX_SENT; }
        if (lane == 0) {
            wV[w][r] = bv;
            wI[w][r] = bi;
        }
    }
    if (lane == 0) wCnt[w] = cnt;
    __syncthreads();

    // wave 0: merge 4 sorted 16-lists = 64 candidates, exactly 1 per lane
    if (w == 0) {
        double mv = wV[lane >> 4][lane & 15];
        int mi = wI[lane >> 4][lane & 15];
        for (int r = 0; r < TOPK; ++r) {
            double bv = mv;
            int bi = mi;
            for (int o = 32; o > 0; o >>= 1) {
                double ov = __shfl_xor(bv, o);
                int oi = __shfl_xor(bi, o);
                if (better(ov, oi, bv, bi)) { bv = ov; bi = oi; }
            }
            if (mi == bi) { mv = -INFINITY; mi = IDX_SENT; }
            if (lane == 0) {
                candV[bx * TOPK + r] = bv;
                candI[bx * TOPK + r] = bi;
            }
        }
        if (lane == 0) cnts[bx] = wCnt[0] + wCnt[1] + wCnt[2] + wCnt[3];
    }
}

// ---------------------------------------------------------------------------
// K2b: one wave per sector. Merge 8 sorted 16-lists (= 128 candidates, 2 per
// lane) by 16 argmax rounds with remove-by-index. Also m and fill indices.
// R10-proven.
// ---------------------------------------------------------------------------
__global__ __launch_bounds__(64) void merge_topk(
    const double* __restrict__ candV, const int* __restrict__ candI,
    const int* __restrict__ cnts, const int* __restrict__ sec,
    const int* __restrict__ act,
    int* __restrict__ top_idx, int* __restrict__ fill_idx,
    int* __restrict__ m_arr)
{
    int c = blockIdx.x;
    int lane = threadIdx.x;

    const double* cbV = candV + (size_t)c * NSL * TOPK;   // 128 entries
    const int* cbI = candI + (size_t)c * NSL * TOPK;
    double v0 = cbV[lane];
    int i0 = cbI[lane];
    double v1 = cbV[lane + 64];
    int i1 = cbI[lane + 64];

    for (int r = 0; r < TOPK; ++r) {
        double bv;
        int bi;
        if (better(v0, i0, v1, i1)) { bv = v0; bi = i0; }
        else                        { bv = v1; bi = i1; }
        for (int o = 32; o > 0; o >>= 1) {
            double ov = __shfl_xor(bv, o);
            int oi = __shfl_xor(bi, o);
            if (better(ov, oi, bv, bi)) { bv = ov; bi = oi; }
        }
        if (i0 == bi)      { v0 = -INFINITY; i0 = IDX_SENT; }
        else if (i1 == bi) { v1 = -INFINITY; i1 = IDX_SENT; }
        if (lane == 0) top_idx[c * TOPK + r] = (bi == IDX_SENT) ? -1 : bi;
    }

    // m = min(16, total active in sector)
    int cl = (lane < NSL) ? cnts[c * NSL + lane] : 0;
    for (int o = 32; o > 0; o >>= 1) cl += __shfl_xor(cl, o);
    if (lane == 0) m_arr[c] = (cl < TOPK) ? cl : TOPK;

    // fill indices: first 16 j failing the predicate (usually 1 iteration)
    int cnt2 = 0;
    for (int basej = 0; basej < N && cnt2 < TOPK; basej += 64) {
        int j = basej + lane;
        bool fail = !((act[j] != 0) && (sec[j] == c));
        unsigned long long mask = __ballot(fail);
        if (fail) {
            int rank = cnt2 + __popcll(mask & ((1ull << lane) - 1));
            if (rank < TOPK) fill_idx[c * TOPK + rank] = j;
        }
        cnt2 += __popcll(mask);
    }
}

// ---------------------------------------------------------------------------
// K3: write outputs (weight, index-as-float, valid-as-float planes).
// ---------------------------------------------------------------------------
__global__ __launch_bounds__(NT) void write_out(const float* __restrict__ s1f,
                                                const double* __restrict__ s2g,
                                                const int* __restrict__ sec,
                                                const int* __restrict__ act,
                                                const int* __restrict__ top_idx,
                                                const int* __restrict__ fill_idx,
                                                const int* __restrict__ m_arr,
                                                float* __restrict__ out) {
    int gid = blockIdx.x * NT + threadIdx.x;  // N*TOPK total
    int i = gid >> 4;
    int slot = gid & 15;

    float wgt = 0.0f;
    float fidx;
    float fvalid = 0.0f;

    if (act[i] == 0) {
        fidx = (float)slot;  // all -inf row: stable top_k -> indices 0..15
    } else {
        int c = sec[i];
        int m = m_arr[c];
        if (slot < m) {
            int j = top_idx[c * TOPK + slot];
            double x = (double)s1f[i] + s2g[j];
            double attv = (x >= 0.0) ? x : NEG_SLOPE * x;
            wgt = (float)attv;
            fvalid = 1.0f;
            fidx = (float)j;
        } else {
            fidx = (float)fill_idx[c * TOPK + (slot - m)];
        }
    }

    out[gid] = wgt;
    out[N * TOPK + gid] = fidx;
    out[2 * N * TOPK + gid] = fvalid;
}

extern "C" void kernel_launch(void* const* d_in, const int* in_sizes, int n_in,
                              void* d_out, int out_size, void* d_ws, size_t ws_size,
                              hipStream_t stream) {
    const float* E = (const float*)d_in[0];
    const float* W = (const float*)d_in[1];
    const float* a = (const float*)d_in[2];
    const int* sec = (const int*)d_in[3];
    const int* act = (const int*)d_in[4];  // bool input uploaded as int32

    // workspace (~115 KB, 8-byte-aligned first) — within proven range
    char* ws = (char*)d_ws;
    double* s2g = (double*)ws;                     // N f64
    double* candV = s2g + N;                       // NSEC*NSL*TOPK = 1408 f64
    float* s1f = (float*)(candV + NSEC * NSL * TOPK);  // N f32
    int* candI = (int*)(s1f + N);                  // 1408 i32
    int* cnts = candI + NSEC * NSL * TOPK;         // NSEC*NSL = 88
    int* top_idx = cnts + NSEC * NSL;              // NSEC*TOPK
    int* fill_idx = top_idx + NSEC * TOPK;         // NSEC*TOPK
    int* m_arr = fill_idx + NSEC * TOPK;           // NSEC

    float* out = (float*)d_out;

    hipLaunchKernelGGL(compute_v_s, dim3(NB), dim3(NT), 0, stream,
                       E, W, a, s1f, s2g);
    hipLaunchKernelGGL(slice_topk, dim3(NSEC * NSL), dim3(NT), 0, stream,
                       s2g, sec, act, candV, candI, cnts);
    hipLaunchKernelGGL(merge_topk, dim3(NSEC), dim3(64), 0, stream,
                       candV, candI, cnts, sec, act, top_idx, fill_idx, m_arr);
    hipLaunchKernelGGL(write_out, dim3((N * TOPK) / NT), dim3(NT), 0, stream,
                       s1f, s2g, sec, act, top_idx, fill_idx, m_arr, out);
}